// Round 4
// baseline (139.466 us; speedup 1.0000x reference)
//
#include <hip/hip_runtime.h>
#include <hip/hip_bf16.h>

// WaveletLinear: y[b,o] = sum_i w[o,i] * (1 - s^2) * exp(-0.5 s^2),
//   s = (x[b,i] - t[o,i]) / (A_MIN + softplus(sr[o,i]) + EPS)
// Rework: u = K*s^2, K = 0.5*log2(e); e = exp2(-u); contrib = w*e - (w/K)*(u*e).
//
// R4 structure (LDS pipe was the 41us limiter in R2/R3):
//  - wl_prep: params -> ws as pT4[i*1024 + o] = {nti_s, inv_s, w, w/K} (8 MB,
//    same ws footprint R1 proved safe). Transposed so lane=o main-loop loads
//    are perfectly coalesced 1024B global_load_dwordx4 (L1-served, 4-wave reuse).
//  - wl_main: lane = o (64 o/wave), 8 b register-blocked per wave, loop i=0..511.
//    x^T staged ONCE into 64KB LDS; inner loop reads it as 2 wave-uniform
//    broadcast ds_read_b128 (32 B/wave-i-step vs 2048 B in R3).
//    Inner math: 4 packed pairs (v_pk_fma_f32/v_pk_mul_f32) + 8 v_exp_f32.

#define WL_A_MIN 0.001f
#define WL_EPS   1e-8f

constexpr int WL_B = 512;
constexpr int WL_O = 1024;
constexpr int WL_I = 512;

// K = 0.5*log2(e); sqrt(K); 1/K; log2(e); ln(2)
#define WL_SQK  0.84932180553704583800f
#define WL_IK   1.38629436111989061883f
#define WL_L2E  1.44269504088896340736f
#define WL_LN2  0.69314718055994530942f

typedef float v2f __attribute__((ext_vector_type(2)));

__device__ __forceinline__ float fast_exp2(float a) {
#if __has_builtin(__builtin_amdgcn_exp2f)
    return __builtin_amdgcn_exp2f(a);
#else
    return exp2f(a);
#endif
}
__device__ __forceinline__ float fast_log2(float a) {
#if __has_builtin(__builtin_amdgcn_logf)
    return __builtin_amdgcn_logf(a);
#else
    return __log2f(a);
#endif
}
__device__ __forceinline__ float fast_rcp(float a) {
#if __has_builtin(__builtin_amdgcn_rcpf)
    return __builtin_amdgcn_rcpf(a);
#else
    return 1.0f / a;
#endif
}

// Param precompute: pT4[i * WL_O + o]. Thread = 1 o x 16 consecutive i
// (reads use full 64B lines; writes are lane-coalesced 1KB stores).
__global__ __launch_bounds__(256) void wl_prep(
    const float* __restrict__ translation,
    const float* __restrict__ scale_raw,
    const float* __restrict__ weights,
    float4* __restrict__ pT4)
{
    const int lane   = threadIdx.x & 63;
    const int ic     = threadIdx.x >> 6;               // 0..3
    const int o      = blockIdx.x * 64 + lane;
    const int i_base = blockIdx.y * 64 + ic * 16;

    #pragma unroll 4
    for (int k = 0; k < 16; ++k) {
        int i  = i_base + k;
        int gi = o * WL_I + i;
        float t  = translation[gi];
        float sr = scale_raw[gi];
        float w  = weights[gi];
        float ex    = fast_exp2(sr * WL_L2E);          // softplus via hw exp2/log2
        float sp    = fast_log2(1.0f + ex) * WL_LN2;
        float inv   = fast_rcp(WL_A_MIN + sp + WL_EPS);
        float inv_s = inv * WL_SQK;
        pT4[i * WL_O + o] = make_float4(-t * inv_s, inv_s, w, w * WL_IK);
    }
}

// Main: grid (O/64=16, B/32=16) = 256 blocks (1/CU), 256 thr = 4 waves.
// All 4 waves share the o-slab (param L1 reuse); wave wid owns b-octet wid*8.
// gx%8 -> XCD: each o-slab (512KB) lives on one XCD's L2.
__global__ __launch_bounds__(256, 1) void wl_main(
    const float* __restrict__ x,
    const float4* __restrict__ pT4,
    float* __restrict__ out)
{
    __shared__ float xT[WL_I * 32];                    // 64 KB: xT[i][b_local]

    const int tid  = threadIdx.x;
    const int lane = tid & 63;
    const int wid  = __builtin_amdgcn_readfirstlane(tid >> 6);  // wave-uniform SGPR
    const int o    = blockIdx.x * 64 + lane;
    const int b0   = blockIdx.y * 32;

    // ---- stage x^T once: lane = b_local -> conflict-free LDS writes ----
    {
        const int b_l = tid & 31;
        const int seg = tid >> 5;                      // 0..7 -> i in [seg*64, +64)
        const float* xg = &x[(b0 + b_l) * WL_I + seg * 64];
        #pragma unroll
        for (int q = 0; q < 16; ++q) {
            float4 v = *reinterpret_cast<const float4*>(xg + q * 4);
            int i0 = seg * 64 + q * 4;
            xT[(i0 + 0) * 32 + b_l] = v.x;
            xT[(i0 + 1) * 32 + b_l] = v.y;
            xT[(i0 + 2) * 32 + b_l] = v.z;
            xT[(i0 + 3) * 32 + b_l] = v.w;
        }
    }
    __syncthreads();

    const float4* pp   = pT4 + o;                      // stride WL_O per i
    const float*  xrow = &xT[wid * 8];                 // uniform base for this wave

    v2f a0 = {0.f, 0.f}, a1 = {0.f, 0.f}, a2 = {0.f, 0.f}, a3 = {0.f, 0.f};

    #pragma unroll 4
    for (int i = 0; i < WL_I; ++i) {
        float4 p = pp[(size_t)i * WL_O];               // coalesced 1024B wave-load
        // wave-uniform broadcast reads: 2 x ds_read_b128 (32 B total)
        float4 xa = *reinterpret_cast<const float4*>(xrow + i * 32);
        float4 xb = *reinterpret_cast<const float4*>(xrow + i * 32 + 4);

        v2f nti = {p.x, p.x};
        v2f inv = {p.y, p.y};
        v2f w2  = {p.z, p.z};
        v2f wk  = {p.w, p.w};

        v2f x01 = {xa.x, xa.y};
        v2f x23 = {xa.z, xa.w};
        v2f x45 = {xb.x, xb.y};
        v2f x67 = {xb.z, xb.w};

        v2f s0 = __builtin_elementwise_fma(x01, inv, nti);
        v2f s1 = __builtin_elementwise_fma(x23, inv, nti);
        v2f s2 = __builtin_elementwise_fma(x45, inv, nti);
        v2f s3 = __builtin_elementwise_fma(x67, inv, nti);
        v2f u0 = s0 * s0;
        v2f u1 = s1 * s1;
        v2f u2 = s2 * s2;
        v2f u3 = s3 * s3;
        v2f e0 = {fast_exp2(-u0.x), fast_exp2(-u0.y)};
        v2f e1 = {fast_exp2(-u1.x), fast_exp2(-u1.y)};
        v2f e2 = {fast_exp2(-u2.x), fast_exp2(-u2.y)};
        v2f e3 = {fast_exp2(-u3.x), fast_exp2(-u3.y)};
        a0 = __builtin_elementwise_fma(w2, e0, a0);
        a1 = __builtin_elementwise_fma(w2, e1, a1);
        a2 = __builtin_elementwise_fma(w2, e2, a2);
        a3 = __builtin_elementwise_fma(w2, e3, a3);
        a0 = __builtin_elementwise_fma(wk, -(u0 * e0), a0);  // neg folds into fma
        a1 = __builtin_elementwise_fma(wk, -(u1 * e1), a1);
        a2 = __builtin_elementwise_fma(wk, -(u2 * e2), a2);
        a3 = __builtin_elementwise_fma(wk, -(u3 * e3), a3);
    }

    const int b = b0 + wid * 8;
    out[(b + 0) * WL_O + o] = a0.x;
    out[(b + 1) * WL_O + o] = a0.y;
    out[(b + 2) * WL_O + o] = a1.x;
    out[(b + 3) * WL_O + o] = a1.y;
    out[(b + 4) * WL_O + o] = a2.x;
    out[(b + 5) * WL_O + o] = a2.y;
    out[(b + 6) * WL_O + o] = a3.x;
    out[(b + 7) * WL_O + o] = a3.y;
}

extern "C" void kernel_launch(void* const* d_in, const int* in_sizes, int n_in,
                              void* d_out, int out_size, void* d_ws, size_t ws_size,
                              hipStream_t stream) {
    const float* x           = (const float*)d_in[0];
    const float* translation = (const float*)d_in[1];
    const float* scale_raw   = (const float*)d_in[2];
    const float* weights     = (const float*)d_in[3];
    float*       out         = (float*)d_out;
    float4*      pT4         = (float4*)d_ws;          // 8 MB (same as R1)

    wl_prep<<<dim3(WL_O / 64, WL_I / 64), dim3(256), 0, stream>>>(
        translation, scale_raw, weights, pT4);

    wl_main<<<dim3(WL_O / 64, WL_B / 32), dim3(256), 0, stream>>>(
        x, pT4, out);
}

// Round 5
// 111.887 us; speedup vs baseline: 1.2465x; 1.2465x over previous
//
#include <hip/hip_runtime.h>
#include <hip/hip_bf16.h>

// WaveletLinear: y[b,o] = sum_i w[o,i] * (1 - s^2) * exp(-0.5 s^2),
//   s = (x[b,i] - t[o,i]) / (A_MIN + softplus(sr[o,i]) + EPS)
// Rework: u = K*s^2, K = 0.5*log2(e); e = exp2(-u);
//   y = sum w*e - (1/K) * sum w*(u*e)   (split accumulators E and U)
//
// R5: R4's low-traffic structure (lane=o, coalesced param loads, x broadcast
// from LDS) + real occupancy. Block = 512 thr (8 waves), b-tile 16; wave =
// (b-octet) x (i-quarter of 128). Grid 512 -> 2 blocks/CU -> 4 waves/SIMD
// (R4 had 1 — its 41% VALUBusy was exposed load latency).
// Params stored as 12B {nti, inv, w} (split-acc makes w/K unnecessary).

#define WL_A_MIN 0.001f
#define WL_EPS   1e-8f

constexpr int WL_B = 512;
constexpr int WL_O = 1024;
constexpr int WL_I = 512;

// K = 0.5*log2(e); sqrt(K); 1/K; log2(e); ln(2)
#define WL_SQK  0.84932180553704583800f
#define WL_IK   1.38629436111989061883f
#define WL_L2E  1.44269504088896340736f
#define WL_LN2  0.69314718055994530942f

typedef float v2f __attribute__((ext_vector_type(2)));

struct P3 { float nti, inv, w; };          // 12 B

__device__ __forceinline__ float fast_exp2(float a) {
#if __has_builtin(__builtin_amdgcn_exp2f)
    return __builtin_amdgcn_exp2f(a);
#else
    return exp2f(a);
#endif
}
__device__ __forceinline__ float fast_log2(float a) {
#if __has_builtin(__builtin_amdgcn_logf)
    return __builtin_amdgcn_logf(a);
#else
    return __log2f(a);
#endif
}
__device__ __forceinline__ float fast_rcp(float a) {
#if __has_builtin(__builtin_amdgcn_rcpf)
    return __builtin_amdgcn_rcpf(a);
#else
    return 1.0f / a;
#endif
}

// Param precompute into ws: pT3[i * WL_O + o]. Lane = o; per-lane i-chunks,
// reads L1-absorbed, writes 768B/wave coalesced.
__global__ __launch_bounds__(256) void wl_prep(
    const float* __restrict__ translation,
    const float* __restrict__ scale_raw,
    const float* __restrict__ weights,
    P3* __restrict__ pT3)
{
    const int lane   = threadIdx.x & 63;
    const int ic     = threadIdx.x >> 6;               // 0..3
    const int o      = blockIdx.x * 64 + lane;
    const int i_base = blockIdx.y * 64 + ic * 16;

    #pragma unroll 4
    for (int k = 0; k < 16; ++k) {
        int i  = i_base + k;
        int gi = o * WL_I + i;
        float t  = translation[gi];
        float sr = scale_raw[gi];
        float w  = weights[gi];
        float ex    = fast_exp2(sr * WL_L2E);          // softplus via hw exp2/log2
        float sp    = fast_log2(1.0f + ex) * WL_LN2;
        float inv   = fast_rcp(WL_A_MIN + sp + WL_EPS);
        float inv_s = inv * WL_SQK;
        P3 pv; pv.nti = -t * inv_s; pv.inv = inv_s; pv.w = w;
        pT3[(size_t)i * WL_O + o] = pv;
    }
}

// Main: grid (O/64=16, B/16=32) = 512 blocks (2/CU), 512 thr = 8 waves.
// Wave wid: oct = wid&1 (which 8 of the 16 b), iq = wid>>1 (i-quarter of 128).
// gx-major linear ids -> each o-slab stays on one XCD's L2; 2 blocks/CU share
// the same o-slab (L1 param reuse).
__global__ __launch_bounds__(512, 4) void wl_main(
    const float* __restrict__ x,
    const P3* __restrict__ pT3,
    float* __restrict__ out)
{
    __shared__ float smem[WL_I * 16];                  // 32 KB: xT[i][b_l]

    const int tid  = threadIdx.x;
    const int lane = tid & 63;
    const int wid  = tid >> 6;                         // 0..7
    const int o    = blockIdx.x * 64 + lane;
    const int b0   = blockIdx.y * 16;

    // ---- stage x^T once: xT[i*16 + b_l]; 4-way write conflicts, one-time ----
    {
        const int b_l = tid & 15;
        const int seg = tid >> 4;                      // 0..31 -> i in [seg*16,+16)
        const float* xg = &x[(b0 + b_l) * WL_I + seg * 16];
        #pragma unroll
        for (int q = 0; q < 4; ++q) {
            float4 v = *reinterpret_cast<const float4*>(xg + q * 4);
            int i0 = seg * 16 + q * 4;
            smem[(i0 + 0) * 16 + b_l] = v.x;
            smem[(i0 + 1) * 16 + b_l] = v.y;
            smem[(i0 + 2) * 16 + b_l] = v.z;
            smem[(i0 + 3) * 16 + b_l] = v.w;
        }
    }
    __syncthreads();

    const int oct = wid & 1;
    const int iq  = wid >> 1;                          // 0..3
    const P3*    pp   = pT3 + o;
    const float* xrow = &smem[oct * 8];                // uniform per wave

    v2f aE0 = {0.f,0.f}, aE1 = {0.f,0.f}, aE2 = {0.f,0.f}, aE3 = {0.f,0.f};
    v2f aU0 = {0.f,0.f}, aU1 = {0.f,0.f}, aU2 = {0.f,0.f}, aU3 = {0.f,0.f};

    const int iBeg = iq * 128;
    #pragma unroll 4
    for (int ii = 0; ii < 128; ++ii) {
        const int i = iBeg + ii;
        P3 p = pp[(size_t)i * WL_O];                   // 768B/wave coalesced
        float4 xa = *reinterpret_cast<const float4*>(xrow + i * 16);     // uniform
        float4 xb = *reinterpret_cast<const float4*>(xrow + i * 16 + 4); // uniform

        v2f nti = {p.nti, p.nti};
        v2f inv = {p.inv, p.inv};
        v2f wv  = {p.w,  p.w};

        v2f x01 = {xa.x, xa.y};
        v2f x23 = {xa.z, xa.w};
        v2f x45 = {xb.x, xb.y};
        v2f x67 = {xb.z, xb.w};

        v2f s0 = __builtin_elementwise_fma(x01, inv, nti);
        v2f s1 = __builtin_elementwise_fma(x23, inv, nti);
        v2f s2 = __builtin_elementwise_fma(x45, inv, nti);
        v2f s3 = __builtin_elementwise_fma(x67, inv, nti);
        v2f u0 = s0 * s0;
        v2f u1 = s1 * s1;
        v2f u2 = s2 * s2;
        v2f u3 = s3 * s3;
        v2f e0 = {fast_exp2(-u0.x), fast_exp2(-u0.y)};
        v2f e1 = {fast_exp2(-u1.x), fast_exp2(-u1.y)};
        v2f e2 = {fast_exp2(-u2.x), fast_exp2(-u2.y)};
        v2f e3 = {fast_exp2(-u3.x), fast_exp2(-u3.y)};
        aE0 = __builtin_elementwise_fma(wv, e0, aE0);
        aE1 = __builtin_elementwise_fma(wv, e1, aE1);
        aE2 = __builtin_elementwise_fma(wv, e2, aE2);
        aE3 = __builtin_elementwise_fma(wv, e3, aE3);
        v2f ue0 = u0 * e0;
        v2f ue1 = u1 * e1;
        v2f ue2 = u2 * e2;
        v2f ue3 = u3 * e3;
        aU0 = __builtin_elementwise_fma(wv, ue0, aU0);
        aU1 = __builtin_elementwise_fma(wv, ue1, aU1);
        aU2 = __builtin_elementwise_fma(wv, ue2, aU2);
        aU3 = __builtin_elementwise_fma(wv, ue3, aU3);
    }

    // ---- reduce i-quarters: waves iq=1..3 dump, iq=0 combines + stores ----
    __syncthreads();                                   // done reading xT
    constexpr int RS = 20;                             // row stride (floats), bank-spread
    if (iq != 0) {
        float4* dst = reinterpret_cast<float4*>(
            &smem[(((iq - 1) * 2 + oct) * 64 + lane) * RS]);
        dst[0] = make_float4(aE0.x, aE0.y, aE1.x, aE1.y);
        dst[1] = make_float4(aE2.x, aE2.y, aE3.x, aE3.y);
        dst[2] = make_float4(aU0.x, aU0.y, aU1.x, aU1.y);
        dst[3] = make_float4(aU2.x, aU2.y, aU3.x, aU3.y);
    }
    __syncthreads();
    if (iq == 0) {
        float E[8] = {aE0.x, aE0.y, aE1.x, aE1.y, aE2.x, aE2.y, aE3.x, aE3.y};
        float U[8] = {aU0.x, aU0.y, aU1.x, aU1.y, aU2.x, aU2.y, aU3.x, aU3.y};
        #pragma unroll
        for (int q = 1; q < 4; ++q) {
            const float4* src = reinterpret_cast<const float4*>(
                &smem[(((q - 1) * 2 + oct) * 64 + lane) * RS]);
            float4 v0 = src[0], v1 = src[1], v2 = src[2], v3 = src[3];
            E[0] += v0.x; E[1] += v0.y; E[2] += v0.z; E[3] += v0.w;
            E[4] += v1.x; E[5] += v1.y; E[6] += v1.z; E[7] += v1.w;
            U[0] += v2.x; U[1] += v2.y; U[2] += v2.z; U[3] += v2.w;
            U[4] += v3.x; U[5] += v3.y; U[6] += v3.z; U[7] += v3.w;
        }
        const int b = b0 + oct * 8;
        #pragma unroll
        for (int k = 0; k < 8; ++k)
            out[(size_t)(b + k) * WL_O + o] = fmaf(-WL_IK, U[k], E[k]);
    }
}

extern "C" void kernel_launch(void* const* d_in, const int* in_sizes, int n_in,
                              void* d_out, int out_size, void* d_ws, size_t ws_size,
                              hipStream_t stream) {
    const float* x           = (const float*)d_in[0];
    const float* translation = (const float*)d_in[1];
    const float* scale_raw   = (const float*)d_in[2];
    const float* weights     = (const float*)d_in[3];
    float*       out         = (float*)d_out;
    P3*          pT3         = (P3*)d_ws;              // 6.3 MB (<= 8 MB, R1-proven)

    wl_prep<<<dim3(WL_O / 64, WL_I / 64), dim3(256), 0, stream>>>(
        translation, scale_raw, weights, pT3);

    wl_main<<<dim3(WL_O / 64, WL_B / 16), dim3(512), 0, stream>>>(
        x, pT3, out);
}